// Round 1
// baseline (978.327 us; speedup 1.0000x reference)
//
#include <hip/hip_runtime.h>

#define NTOT 2048
#define BSZ 16
#define NNODE 128
#define INF 64
#define HD 256
#define EHD 128
#define ONF 64
#define NL 4
#define M1STR 68  // padded LDS stride for m1T (k-major), breaks transpose-write conflicts

__device__ __forceinline__ float silu_f(float v) {
    return v / (1.0f + __expf(-v));
}

// x[ntot,HD] = h[ntot,INF] @ w_in + b_in
__global__ __launch_bounds__(256) void k_embed(const float* __restrict__ h,
        const float* __restrict__ w_in, const float* __restrict__ b_in,
        float* __restrict__ x) {
    __shared__ float hs[INF];
    const int n = blockIdx.x;
    const int t = threadIdx.x;
    if (t < INF) hs[t] = h[n * INF + t];
    __syncthreads();
    float acc = b_in[t];
#pragma unroll 8
    for (int k = 0; k < INF; ++k)
        acc = fmaf(hs[k], w_in[k * HD + t], acc);
    x[n * HD + t] = acc;
}

// A[n,j] = be1[j] + sum_k x[n,k]*we1[l][k][j]     (j<128)
// B[n,j] =          sum_k x[n,k]*we1[l][HD+k][j]
__global__ __launch_bounds__(256) void k_ab(const float* __restrict__ x,
        const float* __restrict__ we1, const float* __restrict__ be1,
        float* __restrict__ A, float* __restrict__ B, int l) {
    __shared__ float xT[HD * 8];  // [k][nn]
    const int t = threadIdx.x;
    const int n0 = blockIdx.x * 8;
#pragma unroll
    for (int i = 0; i < 8; ++i) {
        int idx = i * 256 + t;           // 0..2047
        int nn = idx & 7, k = idx >> 3;
        xT[idx] = x[(n0 + nn) * HD + k];
    }
    __syncthreads();
    const float* wbase;
    float* obase;
    int j;
    float bias;
    if (t < EHD) { j = t;       wbase = we1 + (size_t)l * 2 * HD * EHD;            bias = be1[l * EHD + j]; obase = A; }
    else         { j = t - EHD; wbase = we1 + (size_t)l * 2 * HD * EHD + HD * EHD; bias = 0.0f;             obase = B; }
    float acc[8];
#pragma unroll
    for (int nn = 0; nn < 8; ++nn) acc[nn] = bias;
#pragma unroll 4
    for (int k = 0; k < HD; ++k) {
        float w = wbase[k * EHD + j];
        const float4 a0 = *(const float4*)&xT[k * 8];
        const float4 a1 = *(const float4*)&xT[k * 8 + 4];
        acc[0] = fmaf(a0.x, w, acc[0]);
        acc[1] = fmaf(a0.y, w, acc[1]);
        acc[2] = fmaf(a0.z, w, acc[2]);
        acc[3] = fmaf(a0.w, w, acc[3]);
        acc[4] = fmaf(a1.x, w, acc[4]);
        acc[5] = fmaf(a1.y, w, acc[5]);
        acc[6] = fmaf(a1.z, w, acc[6]);
        acc[7] = fmaf(a1.w, w, acc[7]);
    }
#pragma unroll
    for (int nn = 0; nn < 8; ++nn) obase[(n0 + nn) * EHD + j] = acc[nn];
}

// per receiver node n: agg[n,:] = sum_{c != r} silu( silu(A[n]+B[c]) @ we2 + be2 )
// block = 256 threads = 16 col-tiles(8) x 16 sender-tiles(4); senders done in 2 passes of 64
__global__ __launch_bounds__(256) void k_edge(const float* __restrict__ A,
        const float* __restrict__ B, const float* __restrict__ we2,
        const float* __restrict__ be2, float* __restrict__ agg, int l) {
    __shared__ float m1T[EHD * M1STR];  // [k][c], c in 0..63, padded stride 68
    __shared__ float Ald[EHD];
    __shared__ float red[16 * EHD];
    const int n = blockIdx.x;
    const int b0 = n & ~127;   // graph base node
    const int r = n & 127;
    const int t = threadIdx.x;
    const int ct = t & 15, st = t >> 4;
    const int j0 = ct * 8;
    const int st4 = st * 4;
    const float* w2 = we2 + (size_t)l * EHD * EHD;
    float be2v[8];
#pragma unroll
    for (int jj = 0; jj < 8; ++jj) be2v[jj] = be2[l * EHD + j0 + jj];
    if (t < EHD) Ald[t] = A[n * EHD + t];
    float colsum[8];
#pragma unroll
    for (int jj = 0; jj < 8; ++jj) colsum[jj] = 0.0f;

    for (int pass = 0; pass < 2; ++pass) {
        const int c0 = pass * 64;
        __syncthreads();  // Ald ready (pass0) / previous-pass readers done
        // phase 1: m1T[k][c] = silu(A[k] + B[b0+c0+c][k])
#pragma unroll
        for (int i = 0; i < 32; ++i) {
            int idx = i * 256 + t;            // 0..8191
            int k = idx & 127, c = idx >> 7;  // c in 0..63
            float v = Ald[k] + B[(b0 + c0 + c) * EHD + k];
            m1T[k * M1STR + c] = silu_f(v);
        }
        __syncthreads();
        float acc[4][8];
#pragma unroll
        for (int ss = 0; ss < 4; ++ss)
#pragma unroll
            for (int jj = 0; jj < 8; ++jj) acc[ss][jj] = 0.0f;
#pragma unroll 4
        for (int k = 0; k < EHD; ++k) {
            const float4 a = *(const float4*)&m1T[k * M1STR + st4];
            const float* w2k = w2 + k * EHD;
            const float4 w0 = *(const float4*)&w2k[j0];
            const float4 w1 = *(const float4*)&w2k[j0 + 4];
            const float av[4] = {a.x, a.y, a.z, a.w};
            const float wv[8] = {w0.x, w0.y, w0.z, w0.w, w1.x, w1.y, w1.z, w1.w};
#pragma unroll
            for (int ss = 0; ss < 4; ++ss)
#pragma unroll
                for (int jj = 0; jj < 8; ++jj)
                    acc[ss][jj] = fmaf(av[ss], wv[jj], acc[ss][jj]);
        }
        // epilogue: silu + sum over this thread's senders (skip c==r)
#pragma unroll
        for (int ss = 0; ss < 4; ++ss) {
            int c = c0 + st4 + ss;
            if (c == r) continue;
#pragma unroll
            for (int jj = 0; jj < 8; ++jj)
                colsum[jj] += silu_f(acc[ss][jj] + be2v[jj]);
        }
    }
    // cross-thread reduce over the 16 sender-tile groups
    *(float4*)&red[st * EHD + j0]     = make_float4(colsum[0], colsum[1], colsum[2], colsum[3]);
    *(float4*)&red[st * EHD + j0 + 4] = make_float4(colsum[4], colsum[5], colsum[6], colsum[7]);
    __syncthreads();
    if (t < EHD) {
        float s = 0.0f;
#pragma unroll
        for (int g = 0; g < 16; ++g) s += red[g * EHD + t];
        agg[n * EHD + t] = s;
    }
}

// node update: u = silu([x,agg]@wn1+bn1); u = u@wn2+bn2; x += u   (8 nodes/block)
__global__ __launch_bounds__(256) void k_node(float* __restrict__ x,
        const float* __restrict__ agg, const float* __restrict__ wn1,
        const float* __restrict__ bn1, const float* __restrict__ wn2,
        const float* __restrict__ bn2, int l) {
    __shared__ float catT[(HD + EHD) * 8];  // [k][nn], k<384
    __shared__ float u1T[HD * 8];           // [k][nn]
    const int t = threadIdx.x;
    const int n0 = blockIdx.x * 8;
#pragma unroll
    for (int i = 0; i < 12; ++i) {
        int idx = i * 256 + t;            // 0..3071
        int nn = idx & 7, k = idx >> 3;   // k<384
        float v = (k < HD) ? x[(n0 + nn) * HD + k] : agg[(n0 + nn) * EHD + (k - HD)];
        catT[idx] = v;
    }
    __syncthreads();
    const int j = t;
    float pre[8];
#pragma unroll
    for (int nn = 0; nn < 8; ++nn) pre[nn] = bn1[l * HD + j];
#pragma unroll 4
    for (int k = 0; k < HD + EHD; ++k) {
        float w = wn1[((size_t)l * (HD + EHD) + k) * HD + j];
        const float4 a0 = *(const float4*)&catT[k * 8];
        const float4 a1 = *(const float4*)&catT[k * 8 + 4];
        pre[0] = fmaf(a0.x, w, pre[0]);
        pre[1] = fmaf(a0.y, w, pre[1]);
        pre[2] = fmaf(a0.z, w, pre[2]);
        pre[3] = fmaf(a0.w, w, pre[3]);
        pre[4] = fmaf(a1.x, w, pre[4]);
        pre[5] = fmaf(a1.y, w, pre[5]);
        pre[6] = fmaf(a1.z, w, pre[6]);
        pre[7] = fmaf(a1.w, w, pre[7]);
    }
    float4 s0 = make_float4(silu_f(pre[0]), silu_f(pre[1]), silu_f(pre[2]), silu_f(pre[3]));
    float4 s1 = make_float4(silu_f(pre[4]), silu_f(pre[5]), silu_f(pre[6]), silu_f(pre[7]));
    *(float4*)&u1T[j * 8]     = s0;
    *(float4*)&u1T[j * 8 + 4] = s1;
    __syncthreads();
    float pre2[8];
#pragma unroll
    for (int nn = 0; nn < 8; ++nn) pre2[nn] = bn2[l * HD + j];
#pragma unroll 4
    for (int k = 0; k < HD; ++k) {
        float w = wn2[((size_t)l * HD + k) * HD + j];
        const float4 a0 = *(const float4*)&u1T[k * 8];
        const float4 a1 = *(const float4*)&u1T[k * 8 + 4];
        pre2[0] = fmaf(a0.x, w, pre2[0]);
        pre2[1] = fmaf(a0.y, w, pre2[1]);
        pre2[2] = fmaf(a0.z, w, pre2[2]);
        pre2[3] = fmaf(a0.w, w, pre2[3]);
        pre2[4] = fmaf(a1.x, w, pre2[4]);
        pre2[5] = fmaf(a1.y, w, pre2[5]);
        pre2[6] = fmaf(a1.z, w, pre2[6]);
        pre2[7] = fmaf(a1.w, w, pre2[7]);
    }
#pragma unroll
    for (int nn = 0; nn < 8; ++nn)
        x[(n0 + nn) * HD + j] = catT[j * 8 + nn] + pre2[nn];
}

// out[ntot,ONF] = x @ w_out + b_out   (4 nodes/block)
__global__ __launch_bounds__(256) void k_out(const float* __restrict__ x,
        const float* __restrict__ w_out, const float* __restrict__ b_out,
        float* __restrict__ out) {
    __shared__ float xs[4 * HD];
    const int t = threadIdx.x;
    const int n0 = blockIdx.x * 4;
#pragma unroll
    for (int i = 0; i < 4; ++i) {
        int idx = i * 256 + t;            // 0..1023
        int nn = idx >> 8, k = idx & 255;
        xs[idx] = x[(n0 + nn) * HD + k];
    }
    __syncthreads();
    const int nn = t >> 6, j = t & 63;
    float acc = b_out[j];
#pragma unroll 4
    for (int k = 0; k < HD; ++k)
        acc = fmaf(xs[nn * HD + k], w_out[k * ONF + j], acc);
    out[(n0 + nn) * ONF + j] = acc;
}

extern "C" void kernel_launch(void* const* d_in, const int* in_sizes, int n_in,
                              void* d_out, int out_size, void* d_ws, size_t ws_size,
                              hipStream_t stream) {
    const float* h     = (const float*)d_in[0];
    // d_in[1]=rows, d_in[2]=cols: fully-connected structure is analytic; unused
    const float* w_in  = (const float*)d_in[3];
    const float* b_in  = (const float*)d_in[4];
    const float* w_out = (const float*)d_in[5];
    const float* b_out = (const float*)d_in[6];
    const float* we1   = (const float*)d_in[7];
    const float* be1   = (const float*)d_in[8];
    const float* we2   = (const float*)d_in[9];
    const float* be2   = (const float*)d_in[10];
    const float* wn1   = (const float*)d_in[11];
    const float* bn1   = (const float*)d_in[12];
    const float* wn2   = (const float*)d_in[13];
    const float* bn2   = (const float*)d_in[14];

    float* ws  = (float*)d_ws;
    float* x   = ws;                      // 2048*256
    float* A   = x + NTOT * HD;           // 2048*128
    float* B   = A + NTOT * EHD;          // 2048*128
    float* agg = B + NTOT * EHD;          // 2048*128
    float* out = (float*)d_out;

    k_embed<<<NTOT, 256, 0, stream>>>(h, w_in, b_in, x);
    for (int l = 0; l < NL; ++l) {
        k_ab<<<NTOT / 8, 256, 0, stream>>>(x, we1, be1, A, B, l);
        k_edge<<<NTOT, 256, 0, stream>>>(A, B, we2, be2, agg, l);
        k_node<<<NTOT / 8, 256, 0, stream>>>(x, agg, wn1, bn1, wn2, bn2, l);
    }
    k_out<<<NTOT / 4, 256, 0, stream>>>(x, w_out, b_out, out);
}

// Round 2
// 513.379 us; speedup vs baseline: 1.9057x; 1.9057x over previous
//
#include <hip/hip_runtime.h>

#define NTOT 2048
#define INF 64
#define HD 256
#define EHD 128
#define ONF 64
#define NL 4

typedef __attribute__((ext_vector_type(8))) short bf16x8;
typedef __attribute__((ext_vector_type(4))) float f32x4;

__device__ __forceinline__ float silu_f(float v) {
    return v / (1.0f + __expf(-v));
}

__device__ __forceinline__ unsigned short f2bf(float f) {
    unsigned int u = __float_as_uint(f);
    u += 0x7FFFu + ((u >> 16) & 1u);
    return (unsigned short)(u >> 16);
}

__device__ __forceinline__ void split_bf(float v, unsigned short& h, unsigned short& l) {
    h = f2bf(v);
    float hv = __uint_as_float(((unsigned int)h) << 16);
    l = f2bf(v - hv);
}

// ---------------- embedding in ----------------
__global__ __launch_bounds__(256) void k_embed(const float* __restrict__ h,
        const float* __restrict__ w_in, const float* __restrict__ b_in,
        float* __restrict__ x) {
    __shared__ float hs[INF];
    const int n = blockIdx.x;
    const int t = threadIdx.x;
    if (t < INF) hs[t] = h[n * INF + t];
    __syncthreads();
    float acc = b_in[t];
#pragma unroll 8
    for (int k = 0; k < INF; ++k)
        acc = fmaf(hs[k], w_in[k * HD + t], acc);
    x[n * HD + t] = acc;
}

// ---------------- A/B projections (edge MLP-1 factorized per node) ----------------
__global__ __launch_bounds__(256) void k_ab(const float* __restrict__ x,
        const float* __restrict__ we1, const float* __restrict__ be1,
        float* __restrict__ A, float* __restrict__ B, int l) {
    __shared__ float xT[HD * 8];  // [k][nn]
    const int t = threadIdx.x;
    const int n0 = blockIdx.x * 8;
#pragma unroll
    for (int i = 0; i < 8; ++i) {
        int idx = i * 256 + t;
        int nn = idx & 7, k = idx >> 3;
        xT[idx] = x[(n0 + nn) * HD + k];
    }
    __syncthreads();
    const float* wbase;
    float* obase;
    int j;
    float bias;
    if (t < EHD) { j = t;       wbase = we1 + (size_t)l * 2 * HD * EHD;            bias = be1[l * EHD + j]; obase = A; }
    else         { j = t - EHD; wbase = we1 + (size_t)l * 2 * HD * EHD + HD * EHD; bias = 0.0f;             obase = B; }
    float acc[8];
#pragma unroll
    for (int nn = 0; nn < 8; ++nn) acc[nn] = bias;
#pragma unroll 4
    for (int k = 0; k < HD; ++k) {
        float w = wbase[k * EHD + j];
        const float4 a0 = *(const float4*)&xT[k * 8];
        const float4 a1 = *(const float4*)&xT[k * 8 + 4];
        acc[0] = fmaf(a0.x, w, acc[0]);
        acc[1] = fmaf(a0.y, w, acc[1]);
        acc[2] = fmaf(a0.z, w, acc[2]);
        acc[3] = fmaf(a0.w, w, acc[3]);
        acc[4] = fmaf(a1.x, w, acc[4]);
        acc[5] = fmaf(a1.y, w, acc[5]);
        acc[6] = fmaf(a1.z, w, acc[6]);
        acc[7] = fmaf(a1.w, w, acc[7]);
    }
#pragma unroll
    for (int nn = 0; nn < 8; ++nn) obase[(n0 + nn) * EHD + j] = acc[nn];
}

// ---------------- we2 hi/lo fragment precompute (all layers) ----------------
// layout: wf[((l*2+copy)*2048 + nt*256 + ks*64 + lane)*8 + i], bf16 raw ushort
// fragment semantics (16x16x32): col j = nt*16 + (lane&15), k = ks*32 + (lane>>4)*8 + i
__global__ __launch_bounds__(256) void k_wfrag(const float* __restrict__ we2,
        short* __restrict__ wf) {
    const int gid = blockIdx.x * 256 + threadIdx.x;   // 0..8191
    const int l = gid >> 11;
    const int slot = gid & 2047;
    const int nt = slot >> 8;
    const int ks = (slot >> 6) & 3;
    const int lane = slot & 63;
    const int j = nt * 16 + (lane & 15);
    const int k0 = ks * 32 + (lane >> 4) * 8;
    const float* w = we2 + (size_t)l * EHD * EHD;
    unsigned short hi[8], lo[8];
#pragma unroll
    for (int i = 0; i < 8; ++i) {
        float f = w[(k0 + i) * EHD + j];
        split_bf(f, hi[i], lo[i]);
    }
    uint4 ph, pl;
    ph.x = (unsigned)hi[0] | ((unsigned)hi[1] << 16);
    ph.y = (unsigned)hi[2] | ((unsigned)hi[3] << 16);
    ph.z = (unsigned)hi[4] | ((unsigned)hi[5] << 16);
    ph.w = (unsigned)hi[6] | ((unsigned)hi[7] << 16);
    pl.x = (unsigned)lo[0] | ((unsigned)lo[1] << 16);
    pl.y = (unsigned)lo[2] | ((unsigned)lo[3] << 16);
    pl.z = (unsigned)lo[4] | ((unsigned)lo[5] << 16);
    pl.w = (unsigned)lo[6] | ((unsigned)lo[7] << 16);
    *(uint4*)&wf[((size_t)(l * 2 + 0) * 2048 + slot) * 8] = ph;
    *(uint4*)&wf[((size_t)(l * 2 + 1) * 2048 + slot) * 8] = pl;
}

// ---------------- edge GEMM + scatter-sum, MFMA ----------------
// block = 1 receiver node, 256 threads = 4 waves; wave w owns j-cols [w*32, w*32+32)
__global__ __launch_bounds__(256, 3) void k_edge_mfma(
        const float* __restrict__ A, const float* __restrict__ B,
        const short* __restrict__ wf, const float* __restrict__ be2,
        float* __restrict__ agg, int l) {
    __shared__ __align__(16) short fr[2][2][4][64][8];  // [copy][mt][ks][lane][i] bf16 raw
    const int n = blockIdx.x;
    const int b0 = n & ~127;
    const int r = n & 127;
    const int t = threadIdx.x;
    const int w = t >> 6;
    const int lane = t & 63;
    const int kg = t & 15;          // k-group for m1 compute (k0 = kg*8)
    const int ksw = kg >> 2;        // ks of this thread's write slot
    const int lanef = ((kg & 3) << 4);  // + (c&15) added per iter

    // A row of this node, 8 floats for this thread's k-group
    float a8[8];
    {
        const float4 a0 = *(const float4*)&A[n * EHD + kg * 8];
        const float4 a1 = *(const float4*)&A[n * EHD + kg * 8 + 4];
        a8[0] = a0.x; a8[1] = a0.y; a8[2] = a0.z; a8[3] = a0.w;
        a8[4] = a1.x; a8[5] = a1.y; a8[6] = a1.z; a8[7] = a1.w;
    }

    // we2 fragments for this wave's 2 N-tiles, hi and lo
    bf16x8 bh[2][4], bl[2][4];
#pragma unroll
    for (int nti = 0; nti < 2; ++nti) {
        const int nt = w * 2 + nti;
#pragma unroll
        for (int ks = 0; ks < 4; ++ks) {
            bh[nti][ks] = *(const bf16x8*)&wf[((size_t)(l * 2 + 0) * 2048 + nt * 256 + ks * 64 + lane) * 8];
            bl[nti][ks] = *(const bf16x8*)&wf[((size_t)(l * 2 + 1) * 2048 + nt * 256 + ks * 64 + lane) * 8];
        }
    }
    float be2v[2];
#pragma unroll
    for (int nti = 0; nti < 2; ++nti)
        be2v[nti] = be2[l * EHD + (w * 2 + nti) * 16 + (lane & 15)];

    float colsum[2] = {0.0f, 0.0f};

    for (int ch = 0; ch < 4; ++ch) {
        __syncthreads();  // previous chunk's MFMA reads done
        // ---- phase 1: m1 = silu(A + B[sender]) -> bf16 hi/lo fragments in LDS
#pragma unroll
        for (int iter = 0; iter < 2; ++iter) {
            const int c_l = iter * 16 + (t >> 4);   // 0..31 chunk-local sender
            const int mtl = c_l >> 4;
            const float* Brow = &B[(size_t)(b0 + ch * 32 + c_l) * EHD + kg * 8];
            const float4 bv0 = *(const float4*)Brow;
            const float4 bv1 = *(const float4*)(Brow + 4);
            float v[8] = {bv0.x + a8[0], bv0.y + a8[1], bv0.z + a8[2], bv0.w + a8[3],
                          bv1.x + a8[4], bv1.y + a8[5], bv1.z + a8[6], bv1.w + a8[7]};
            unsigned short hi[8], lo[8];
#pragma unroll
            for (int i = 0; i < 8; ++i) {
                float s = silu_f(v[i]);
                split_bf(s, hi[i], lo[i]);
            }
            uint4 ph, pl;
            ph.x = (unsigned)hi[0] | ((unsigned)hi[1] << 16);
            ph.y = (unsigned)hi[2] | ((unsigned)hi[3] << 16);
            ph.z = (unsigned)hi[4] | ((unsigned)hi[5] << 16);
            ph.w = (unsigned)hi[6] | ((unsigned)hi[7] << 16);
            pl.x = (unsigned)lo[0] | ((unsigned)lo[1] << 16);
            pl.y = (unsigned)lo[2] | ((unsigned)lo[3] << 16);
            pl.z = (unsigned)lo[4] | ((unsigned)lo[5] << 16);
            pl.w = (unsigned)lo[6] | ((unsigned)lo[7] << 16);
            const int lf = lanef + (c_l & 15);
            *(uint4*)&fr[0][mtl][ksw][lf][0] = ph;
            *(uint4*)&fr[1][mtl][ksw][lf][0] = pl;
        }
        __syncthreads();  // fragments visible
        // ---- phase 2: MFMA + epilogue
#pragma unroll
        for (int mtl = 0; mtl < 2; ++mtl) {
            bf16x8 ah[4], al[4];
#pragma unroll
            for (int ks = 0; ks < 4; ++ks) {
                ah[ks] = *(const bf16x8*)&fr[0][mtl][ks][lane][0];
                al[ks] = *(const bf16x8*)&fr[1][mtl][ks][lane][0];
            }
#pragma unroll
            for (int nti = 0; nti < 2; ++nti) {
                f32x4 acc = {0.0f, 0.0f, 0.0f, 0.0f};
#pragma unroll
                for (int ks = 0; ks < 4; ++ks) {
                    acc = __builtin_amdgcn_mfma_f32_16x16x32_bf16(ah[ks], bh[nti][ks], acc, 0, 0, 0);
                    acc = __builtin_amdgcn_mfma_f32_16x16x32_bf16(al[ks], bh[nti][ks], acc, 0, 0, 0);
                    acc = __builtin_amdgcn_mfma_f32_16x16x32_bf16(ah[ks], bl[nti][ks], acc, 0, 0, 0);
                }
                const int cbase = ch * 32 + mtl * 16 + ((lane >> 4) << 2);
#pragma unroll
                for (int reg = 0; reg < 4; ++reg) {
                    const int c = cbase + reg;
                    float s = silu_f(acc[reg] + be2v[nti]);
                    if (c != r) colsum[nti] += s;
                }
            }
        }
    }
    // cross-lane reduce over row groups (lane>>4): lanes l, l^16, l^32 hold partials
#pragma unroll
    for (int nti = 0; nti < 2; ++nti) {
        float s = colsum[nti];
        s += __shfl_xor(s, 16);
        s += __shfl_xor(s, 32);
        if (lane < 16)
            agg[(size_t)n * EHD + (w * 2 + nti) * 16 + lane] = s;
    }
}

// ---------------- node update ----------------
__global__ __launch_bounds__(256) void k_node(float* __restrict__ x,
        const float* __restrict__ agg, const float* __restrict__ wn1,
        const float* __restrict__ bn1, const float* __restrict__ wn2,
        const float* __restrict__ bn2, int l) {
    __shared__ float catT[(HD + EHD) * 8];
    __shared__ float u1T[HD * 8];
    const int t = threadIdx.x;
    const int n0 = blockIdx.x * 8;
#pragma unroll
    for (int i = 0; i < 12; ++i) {
        int idx = i * 256 + t;
        int nn = idx & 7, k = idx >> 3;
        float v = (k < HD) ? x[(n0 + nn) * HD + k] : agg[(n0 + nn) * EHD + (k - HD)];
        catT[idx] = v;
    }
    __syncthreads();
    const int j = t;
    float pre[8];
#pragma unroll
    for (int nn = 0; nn < 8; ++nn) pre[nn] = bn1[l * HD + j];
#pragma unroll 4
    for (int k = 0; k < HD + EHD; ++k) {
        float w = wn1[((size_t)l * (HD + EHD) + k) * HD + j];
        const float4 a0 = *(const float4*)&catT[k * 8];
        const float4 a1 = *(const float4*)&catT[k * 8 + 4];
        pre[0] = fmaf(a0.x, w, pre[0]);
        pre[1] = fmaf(a0.y, w, pre[1]);
        pre[2] = fmaf(a0.z, w, pre[2]);
        pre[3] = fmaf(a0.w, w, pre[3]);
        pre[4] = fmaf(a1.x, w, pre[4]);
        pre[5] = fmaf(a1.y, w, pre[5]);
        pre[6] = fmaf(a1.z, w, pre[6]);
        pre[7] = fmaf(a1.w, w, pre[7]);
    }
    float4 s0 = make_float4(silu_f(pre[0]), silu_f(pre[1]), silu_f(pre[2]), silu_f(pre[3]));
    float4 s1 = make_float4(silu_f(pre[4]), silu_f(pre[5]), silu_f(pre[6]), silu_f(pre[7]));
    *(float4*)&u1T[j * 8]     = s0;
    *(float4*)&u1T[j * 8 + 4] = s1;
    __syncthreads();
    float pre2[8];
#pragma unroll
    for (int nn = 0; nn < 8; ++nn) pre2[nn] = bn2[l * HD + j];
#pragma unroll 4
    for (int k = 0; k < HD; ++k) {
        float w = wn2[((size_t)l * HD + k) * HD + j];
        const float4 a0 = *(const float4*)&u1T[k * 8];
        const float4 a1 = *(const float4*)&u1T[k * 8 + 4];
        pre2[0] = fmaf(a0.x, w, pre2[0]);
        pre2[1] = fmaf(a0.y, w, pre2[1]);
        pre2[2] = fmaf(a0.z, w, pre2[2]);
        pre2[3] = fmaf(a0.w, w, pre2[3]);
        pre2[4] = fmaf(a1.x, w, pre2[4]);
        pre2[5] = fmaf(a1.y, w, pre2[5]);
        pre2[6] = fmaf(a1.z, w, pre2[6]);
        pre2[7] = fmaf(a1.w, w, pre2[7]);
    }
#pragma unroll
    for (int nn = 0; nn < 8; ++nn)
        x[(n0 + nn) * HD + j] = catT[j * 8 + nn] + pre2[nn];
}

// ---------------- embedding out ----------------
__global__ __launch_bounds__(256) void k_out(const float* __restrict__ x,
        const float* __restrict__ w_out, const float* __restrict__ b_out,
        float* __restrict__ out) {
    __shared__ float xs[4 * HD];
    const int t = threadIdx.x;
    const int n0 = blockIdx.x * 4;
#pragma unroll
    for (int i = 0; i < 4; ++i) {
        int idx = i * 256 + t;
        int nn = idx >> 8, k = idx & 255;
        xs[idx] = x[(n0 + nn) * HD + k];
    }
    __syncthreads();
    const int nn = t >> 6, j = t & 63;
    float acc = b_out[j];
#pragma unroll 4
    for (int k = 0; k < HD; ++k)
        acc = fmaf(xs[nn * HD + k], w_out[k * ONF + j], acc);
    out[(n0 + nn) * ONF + j] = acc;
}

extern "C" void kernel_launch(void* const* d_in, const int* in_sizes, int n_in,
                              void* d_out, int out_size, void* d_ws, size_t ws_size,
                              hipStream_t stream) {
    const float* h     = (const float*)d_in[0];
    const float* w_in  = (const float*)d_in[3];
    const float* b_in  = (const float*)d_in[4];
    const float* w_out = (const float*)d_in[5];
    const float* b_out = (const float*)d_in[6];
    const float* we1   = (const float*)d_in[7];
    const float* be1   = (const float*)d_in[8];
    const float* we2   = (const float*)d_in[9];
    const float* be2   = (const float*)d_in[10];
    const float* wn1   = (const float*)d_in[11];
    const float* bn1   = (const float*)d_in[12];
    const float* wn2   = (const float*)d_in[13];
    const float* bn2   = (const float*)d_in[14];

    float* ws  = (float*)d_ws;
    float* x   = ws;                      // 2048*256
    float* A   = x + NTOT * HD;           // 2048*128
    float* B   = A + NTOT * EHD;          // 2048*128
    float* agg = B + NTOT * EHD;          // 2048*128
    short* wfrag = (short*)(agg + NTOT * EHD);  // 4*2*2048*8 shorts = 256KB
    float* out = (float*)d_out;

    k_wfrag<<<32, 256, 0, stream>>>(we2, wfrag);
    k_embed<<<NTOT, 256, 0, stream>>>(h, w_in, b_in, x);
    for (int l = 0; l < NL; ++l) {
        k_ab<<<NTOT / 8, 256, 0, stream>>>(x, we1, be1, A, B, l);
        k_edge_mfma<<<NTOT, 256, 0, stream>>>(A, B, wfrag, be2, agg, l);
        k_node<<<NTOT / 8, 256, 0, stream>>>(x, agg, wn1, bn1, wn2, bn2, l);
    }
    k_out<<<NTOT / 4, 256, 0, stream>>>(x, w_out, b_out, out);
}

// Round 3
// 330.880 us; speedup vs baseline: 2.9567x; 1.5516x over previous
//
#include <hip/hip_runtime.h>

#define NTOT 2048
#define INF 64
#define HD 256
#define EHD 128
#define ONF 64
#define NL 4

typedef __attribute__((ext_vector_type(8))) short bf16x8;
typedef __attribute__((ext_vector_type(4))) float f32x4;

__device__ __forceinline__ float silu_f(float v) {
    return v * __builtin_amdgcn_rcpf(1.0f + __expf(-v));
}

// rounded split (weights, one-time)
__device__ __forceinline__ unsigned short f2bf_rn(float f) {
    unsigned u = __float_as_uint(f);
    u += 0x7FFFu + ((u >> 16) & 1u);
    return (unsigned short)(u >> 16);
}
__device__ __forceinline__ void split_rn(float v, unsigned short& h, unsigned short& l) {
    h = f2bf_rn(v);
    l = f2bf_rn(v - __uint_as_float((unsigned)h << 16));
}
// truncating split (activations): uh/ul are top-16-masked uints (bf16 in high half)
__device__ __forceinline__ void split_tr(float v, unsigned& uh, unsigned& ul) {
    unsigned u = __float_as_uint(v);
    uh = u & 0xffff0000u;
    ul = __float_as_uint(v - __uint_as_float(uh)) & 0xffff0000u;
}
__device__ __forceinline__ float bfraw2f(unsigned short s) {
    return __uint_as_float((unsigned)s << 16);
}

// ================= weight fragment prep (one launch, all matrices) =================
// frag layout per matrix: slot = (nt*KS + ks)*64 + lane; elem i: W[k][n],
// n = nt*16 + (lane&15), k = ks*32 + (lane>>4)*8 + i
__global__ __launch_bounds__(256) void k_prep(
        const float* __restrict__ w_in, const float* __restrict__ we1,
        const float* __restrict__ wn1, const float* __restrict__ wn2,
        const float* __restrict__ w_out, const float* __restrict__ we2,
        short* __restrict__ hwin, short* __restrict__ lwin,
        short* __restrict__ hwe1, short* __restrict__ lwe1,
        short* __restrict__ hwn1, short* __restrict__ lwn1,
        short* __restrict__ hwn2, short* __restrict__ lwn2,
        short* __restrict__ hwout, short* __restrict__ lwout,
        short* __restrict__ hwe2, short* __restrict__ lwe2) {
    const int gid = blockIdx.x * 256 + threadIdx.x;
    const float* src; short* hd; short* ld;
    int sl, dst, KS, N, mode;
    if (gid < 2048)        { sl = gid;                dst = gid;           src = w_in;                                  hd = hwin;  ld = lwin;  KS = 2;  N = 256; mode = 0; }
    else if (gid < 34816)  { int g = gid - 2048;      sl = g & 8191;  dst = g; src = we1 + (size_t)(g >> 13) * 512 * 128;   hd = hwe1;  ld = lwe1;  KS = 8;  N = 256; mode = 1; }
    else if (gid < 83968)  { int g = gid - 34816;     sl = g % 12288; dst = g; src = wn1 + (size_t)(g / 12288) * 384 * 256; hd = hwn1;  ld = lwn1;  KS = 12; N = 256; mode = 0; }
    else if (gid < 116736) { int g = gid - 83968;     sl = g & 8191;  dst = g; src = wn2 + (size_t)(g >> 13) * 256 * 256;   hd = hwn2;  ld = lwn2;  KS = 8;  N = 256; mode = 0; }
    else if (gid < 118784) { int g = gid - 116736;    sl = g;         dst = g; src = w_out;                                 hd = hwout; ld = lwout; KS = 8;  N = 64;  mode = 0; }
    else if (gid < 126976) { int g = gid - 118784;    sl = g & 2047;  dst = g; src = we2 + (size_t)(g >> 11) * 128 * 128;   hd = hwe2;  ld = lwe2;  KS = 4;  N = 128; mode = 0; }
    else return;
    const int lane = sl & 63;
    const int t2 = sl >> 6;
    const int ks = t2 % KS;
    const int nt = t2 / KS;
    const int n = nt * 16 + (lane & 15);
    const int k0 = ks * 32 + ((lane >> 4) << 3);
    short h8[8], l8[8];
#pragma unroll
    for (int i = 0; i < 8; ++i) {
        int k = k0 + i;
        float f;
        if (mode == 1) f = (n < 128) ? src[(size_t)k * 128 + n] : src[(size_t)(256 + k) * 128 + (n - 128)];
        else           f = src[(size_t)k * N + n];
        unsigned short hh, ll;
        split_rn(f, hh, ll);
        h8[i] = (short)hh; l8[i] = (short)ll;
    }
#pragma unroll
    for (int i = 0; i < 8; ++i) {
        hd[(size_t)dst * 8 + i] = h8[i];
        ld[(size_t)dst * 8 + i] = l8[i];
    }
}

// ================= embed + layer-0 A/B, fused MFMA =================
// grid 128 blocks (16 nodes each), 256 threads = 4 waves; wave w owns cols w*64..w*64+63
__global__ __launch_bounds__(256) void k_embed_ab(
        const float* __restrict__ h, const float* __restrict__ b_in,
        const float* __restrict__ be1,
        const short* __restrict__ hwin, const short* __restrict__ lwin,
        const short* __restrict__ hwe1, const short* __restrict__ lwe1,
        short* __restrict__ xs_hi, short* __restrict__ xs_lo,
        float* __restrict__ A, float* __restrict__ Bb) {
    __shared__ __align__(16) short hls[2][2][64][8];
    __shared__ __align__(16) short xls[2][8][64][8];
    const int t = threadIdx.x;
    const int mt = blockIdx.x;
    const int n0 = mt * 16;
    const int w = t >> 6, lane = t & 63;
    const int r0 = (lane >> 4) * 4;

    // stage h rows -> split frags in LDS
    {
        const int m = t & 15, k0 = (t >> 4) * 4;
        const float4 v4 = *(const float4*)&h[(size_t)(n0 + m) * INF + k0];
        float vv[4] = {v4.x, v4.y, v4.z, v4.w};
        const int ks = k0 >> 5;
        const int lane2 = m + 16 * ((k0 & 31) >> 3);
        const int i0 = k0 & 7;
        unsigned uh[4], ul[4];
#pragma unroll
        for (int i = 0; i < 4; ++i) split_tr(vv[i], uh[i], ul[i]);
        *(uint2*)&hls[0][ks][lane2][i0] = make_uint2((uh[0] >> 16) | uh[1], (uh[2] >> 16) | uh[3]);
        *(uint2*)&hls[1][ks][lane2][i0] = make_uint2((ul[0] >> 16) | ul[1], (ul[2] >> 16) | ul[3]);
    }
    __syncthreads();
    // GEMM0: x = h @ w_in
    f32x4 acc[4];
#pragma unroll
    for (int nti = 0; nti < 4; ++nti) acc[nti] = (f32x4){0.f, 0.f, 0.f, 0.f};
#pragma unroll
    for (int ks = 0; ks < 2; ++ks) {
        bf16x8 ah = *(const bf16x8*)&hls[0][ks][lane][0];
        bf16x8 al = *(const bf16x8*)&hls[1][ks][lane][0];
#pragma unroll
        for (int nti = 0; nti < 4; ++nti) {
            int nt = w * 4 + nti;
            bf16x8 bh = ((const bf16x8*)hwin)[(nt * 2 + ks) * 64 + lane];
            bf16x8 bl = ((const bf16x8*)lwin)[(nt * 2 + ks) * 64 + lane];
            acc[nti] = __builtin_amdgcn_mfma_f32_16x16x32_bf16(ah, bh, acc[nti], 0, 0, 0);
            acc[nti] = __builtin_amdgcn_mfma_f32_16x16x32_bf16(al, bh, acc[nti], 0, 0, 0);
            acc[nti] = __builtin_amdgcn_mfma_f32_16x16x32_bf16(ah, bl, acc[nti], 0, 0, 0);
        }
    }
    // epilogue0: x = acc + b_in -> split into xls
#pragma unroll
    for (int nti = 0; nti < 4; ++nti) {
        int col = w * 64 + nti * 16 + (lane & 15);
        float bias = b_in[col];
        int ks = col >> 5, l2b = 16 * ((col & 31) >> 3), i2 = col & 7;
#pragma unroll
        for (int reg = 0; reg < 4; ++reg) {
            float xv = acc[nti][reg] + bias;
            unsigned uh, ul;
            split_tr(xv, uh, ul);
            xls[0][ks][r0 + reg + l2b][i2] = (short)(uh >> 16);
            xls[1][ks][r0 + reg + l2b][i2] = (short)(ul >> 16);
        }
    }
    __syncthreads();
    // dump xls -> xs global
#pragma unroll
    for (int rep = 0; rep < 4; ++rep) {
        int s = rep * 256 + t;
        int plane = s >> 9, ks = (s >> 6) & 7, ln = s & 63;
        bf16x8 v = *(const bf16x8*)&xls[plane][ks][ln][0];
        bf16x8* dstp = (bf16x8*)(plane ? xs_lo : xs_hi);
        dstp[(size_t)(mt * 8 + ks) * 64 + ln] = v;
    }
    // GEMM1: [A|B] = x @ we1[0]
    f32x4 acc1[4];
#pragma unroll
    for (int nti = 0; nti < 4; ++nti) acc1[nti] = (f32x4){0.f, 0.f, 0.f, 0.f};
#pragma unroll
    for (int ks = 0; ks < 8; ++ks) {
        bf16x8 ah = *(const bf16x8*)&xls[0][ks][lane][0];
        bf16x8 al = *(const bf16x8*)&xls[1][ks][lane][0];
#pragma unroll
        for (int nti = 0; nti < 4; ++nti) {
            int nt = w * 4 + nti;
            bf16x8 bh = ((const bf16x8*)hwe1)[(nt * 8 + ks) * 64 + lane];
            bf16x8 bl = ((const bf16x8*)lwe1)[(nt * 8 + ks) * 64 + lane];
            acc1[nti] = __builtin_amdgcn_mfma_f32_16x16x32_bf16(ah, bh, acc1[nti], 0, 0, 0);
            acc1[nti] = __builtin_amdgcn_mfma_f32_16x16x32_bf16(al, bh, acc1[nti], 0, 0, 0);
            acc1[nti] = __builtin_amdgcn_mfma_f32_16x16x32_bf16(ah, bl, acc1[nti], 0, 0, 0);
        }
    }
#pragma unroll
    for (int nti = 0; nti < 4; ++nti) {
        int j = w * 64 + nti * 16 + (lane & 15);
        float bias = (j < 128) ? be1[j] : 0.0f;
        float* dstp = (j < 128) ? A : Bb;
        int jj = j & 127;
#pragma unroll
        for (int reg = 0; reg < 4; ++reg) {
            int node = n0 + r0 + reg;
            dstp[(size_t)node * 128 + jj] = acc1[nti][reg] + bias;
        }
    }
}

// ================= edge GEMM + scatter-sum, MFMA =================
__global__ __launch_bounds__(256, 3) void k_edge_mfma(
        const float* __restrict__ A, const float* __restrict__ Bb,
        const short* __restrict__ hwe2, const short* __restrict__ lwe2,
        const float* __restrict__ be2, float* __restrict__ agg) {
    __shared__ __align__(16) short fr[2][2][4][64][8];  // [copy][mt][ks][lane][i]
    const int n = blockIdx.x;
    const int b0 = n & ~127;
    const int r = n & 127;
    const int t = threadIdx.x;
    const int w = t >> 6;
    const int lane = t & 63;
    const int kg = t & 15;
    const int ksw = kg >> 2;
    const int lanef = ((kg & 3) << 4);

    float a8[8];
    {
        const float4 a0 = *(const float4*)&A[(size_t)n * EHD + kg * 8];
        const float4 a1 = *(const float4*)&A[(size_t)n * EHD + kg * 8 + 4];
        a8[0] = a0.x; a8[1] = a0.y; a8[2] = a0.z; a8[3] = a0.w;
        a8[4] = a1.x; a8[5] = a1.y; a8[6] = a1.z; a8[7] = a1.w;
    }
    bf16x8 bh[2][4], bl[2][4];
#pragma unroll
    for (int nti = 0; nti < 2; ++nti) {
        const int nt = w * 2 + nti;
#pragma unroll
        for (int ks = 0; ks < 4; ++ks) {
            bh[nti][ks] = ((const bf16x8*)hwe2)[(nt * 4 + ks) * 64 + lane];
            bl[nti][ks] = ((const bf16x8*)lwe2)[(nt * 4 + ks) * 64 + lane];
        }
    }
    float be2v[2];
#pragma unroll
    for (int nti = 0; nti < 2; ++nti)
        be2v[nti] = be2[(w * 2 + nti) * 16 + (lane & 15)];

    float colsum[2] = {0.0f, 0.0f};

    for (int ch = 0; ch < 4; ++ch) {
        __syncthreads();
#pragma unroll
        for (int iter = 0; iter < 2; ++iter) {
            const int c_l = iter * 16 + (t >> 4);
            const int mtl = c_l >> 4;
            const float* Brow = &Bb[(size_t)(b0 + ch * 32 + c_l) * EHD + kg * 8];
            const float4 bv0 = *(const float4*)Brow;
            const float4 bv1 = *(const float4*)(Brow + 4);
            float v[8] = {bv0.x + a8[0], bv0.y + a8[1], bv0.z + a8[2], bv0.w + a8[3],
                          bv1.x + a8[4], bv1.y + a8[5], bv1.z + a8[6], bv1.w + a8[7]};
            unsigned uh[8], ul[8];
#pragma unroll
            for (int i = 0; i < 8; ++i) {
                float s = silu_f(v[i]);
                split_tr(s, uh[i], ul[i]);
            }
            uint4 ph, pl;
            ph.x = (uh[0] >> 16) | uh[1]; ph.y = (uh[2] >> 16) | uh[3];
            ph.z = (uh[4] >> 16) | uh[5]; ph.w = (uh[6] >> 16) | uh[7];
            pl.x = (ul[0] >> 16) | ul[1]; pl.y = (ul[2] >> 16) | ul[3];
            pl.z = (ul[4] >> 16) | ul[5]; pl.w = (ul[6] >> 16) | ul[7];
            const int lf = lanef + (c_l & 15);
            *(uint4*)&fr[0][mtl][ksw][lf][0] = ph;
            *(uint4*)&fr[1][mtl][ksw][lf][0] = pl;
        }
        __syncthreads();
#pragma unroll
        for (int mtl = 0; mtl < 2; ++mtl) {
            bf16x8 ah[4], al[4];
#pragma unroll
            for (int ks = 0; ks < 4; ++ks) {
                ah[ks] = *(const bf16x8*)&fr[0][mtl][ks][lane][0];
                al[ks] = *(const bf16x8*)&fr[1][mtl][ks][lane][0];
            }
#pragma unroll
            for (int nti = 0; nti < 2; ++nti) {
                f32x4 acc = {0.0f, 0.0f, 0.0f, 0.0f};
#pragma unroll
                for (int ks = 0; ks < 4; ++ks) {
                    acc = __builtin_amdgcn_mfma_f32_16x16x32_bf16(ah[ks], bh[nti][ks], acc, 0, 0, 0);
                    acc = __builtin_amdgcn_mfma_f32_16x16x32_bf16(al[ks], bh[nti][ks], acc, 0, 0, 0);
                    acc = __builtin_amdgcn_mfma_f32_16x16x32_bf16(ah[ks], bl[nti][ks], acc, 0, 0, 0);
                }
                const int cbase = ch * 32 + mtl * 16 + ((lane >> 4) << 2);
#pragma unroll
                for (int reg = 0; reg < 4; ++reg) {
                    const int c = cbase + reg;
                    float s = silu_f(acc[reg] + be2v[nti]);
                    if (c != r) colsum[nti] += s;
                }
            }
        }
    }
#pragma unroll
    for (int nti = 0; nti < 2; ++nti) {
        float s = colsum[nti];
        s += __shfl_xor(s, 16);
        s += __shfl_xor(s, 32);
        if (lane < 16)
            agg[(size_t)n * EHD + (w * 2 + nti) * 16 + lane] = s;
    }
}

// ================= node MLP + residual + next-layer A/B (or final out), fused MFMA =================
// grid 128 blocks (16 nodes), 256 threads = 4 waves
__global__ __launch_bounds__(256) void k_node_ab(
        const float* __restrict__ agg,
        const float* __restrict__ bn1, const float* __restrict__ bn2,
        const float* __restrict__ be1, const float* __restrict__ b_out,
        const short* __restrict__ hwn1, const short* __restrict__ lwn1,
        const short* __restrict__ hwn2, const short* __restrict__ lwn2,
        const short* __restrict__ hwe1, const short* __restrict__ lwe1,
        const short* __restrict__ hwout, const short* __restrict__ lwout,
        short* __restrict__ xs_hi, short* __restrict__ xs_lo,
        float* __restrict__ A, float* __restrict__ Bb,
        float* __restrict__ outp, int last) {
    __shared__ __align__(16) short cat[2][12][64][8];  // 24KB  [x | agg] frags
    __shared__ __align__(16) short u1[2][8][64][8];    // 16KB
    __shared__ __align__(16) short xn[2][8][64][8];    // 16KB
    const int t = threadIdx.x;
    const int mt = blockIdx.x;
    const int n0 = mt * 16;
    const int w = t >> 6, lane = t & 63;
    const int r0 = (lane >> 4) * 4;

    // stage x frags (pure copy from xs)
#pragma unroll
    for (int rep = 0; rep < 4; ++rep) {
        int s = rep * 256 + t;
        int plane = s >> 9, ks = (s >> 6) & 7, ln = s & 63;
        const bf16x8* srcp = (const bf16x8*)(plane ? xs_lo : xs_hi);
        bf16x8 v = srcp[(size_t)(mt * 8 + ks) * 64 + ln];
        *(bf16x8*)&cat[plane][ks][ln][0] = v;
    }
    // stage agg rows -> frags at ks 8..11
    {
        const int m = t & 15;
        const int kq = t >> 4;
        const int k0 = kq * 8;
        const float4 v0 = *(const float4*)&agg[(size_t)(n0 + m) * EHD + k0];
        const float4 v1 = *(const float4*)&agg[(size_t)(n0 + m) * EHD + k0 + 4];
        float vv[8] = {v0.x, v0.y, v0.z, v0.w, v1.x, v1.y, v1.z, v1.w};
        const int ks = 8 + (kq >> 2);
        const int lane2 = m + 16 * (kq & 3);
        unsigned uh[8], ul[8];
#pragma unroll
        for (int i = 0; i < 8; ++i) split_tr(vv[i], uh[i], ul[i]);
        uint4 ph, pl;
        ph.x = (uh[0] >> 16) | uh[1]; ph.y = (uh[2] >> 16) | uh[3];
        ph.z = (uh[4] >> 16) | uh[5]; ph.w = (uh[6] >> 16) | uh[7];
        pl.x = (ul[0] >> 16) | ul[1]; pl.y = (ul[2] >> 16) | ul[3];
        pl.z = (ul[4] >> 16) | ul[5]; pl.w = (ul[6] >> 16) | ul[7];
        *(uint4*)&cat[0][ks][lane2][0] = ph;
        *(uint4*)&cat[1][ks][lane2][0] = pl;
    }
    __syncthreads();
    // GEMM1: pre = cat @ wn1[l]  (K=384)
    f32x4 acc[4];
#pragma unroll
    for (int nti = 0; nti < 4; ++nti) acc[nti] = (f32x4){0.f, 0.f, 0.f, 0.f};
#pragma unroll
    for (int ks = 0; ks < 12; ++ks) {
        bf16x8 ah = *(const bf16x8*)&cat[0][ks][lane][0];
        bf16x8 al = *(const bf16x8*)&cat[1][ks][lane][0];
#pragma unroll
        for (int nti = 0; nti < 4; ++nti) {
            int nt = w * 4 + nti;
            bf16x8 bh = ((const bf16x8*)hwn1)[(nt * 12 + ks) * 64 + lane];
            bf16x8 bl = ((const bf16x8*)lwn1)[(nt * 12 + ks) * 64 + lane];
            acc[nti] = __builtin_amdgcn_mfma_f32_16x16x32_bf16(ah, bh, acc[nti], 0, 0, 0);
            acc[nti] = __builtin_amdgcn_mfma_f32_16x16x32_bf16(al, bh, acc[nti], 0, 0, 0);
            acc[nti] = __builtin_amdgcn_mfma_f32_16x16x32_bf16(ah, bl, acc[nti], 0, 0, 0);
        }
    }
    // epilogue1: u1 = silu(pre + bn1)
#pragma unroll
    for (int nti = 0; nti < 4; ++nti) {
        int col = w * 64 + nti * 16 + (lane & 15);
        float bias = bn1[col];
        int ks = col >> 5, l2b = 16 * ((col & 31) >> 3), i2 = col & 7;
#pragma unroll
        for (int reg = 0; reg < 4; ++reg) {
            float uv = silu_f(acc[nti][reg] + bias);
            unsigned uh, ul;
            split_tr(uv, uh, ul);
            u1[0][ks][r0 + reg + l2b][i2] = (short)(uh >> 16);
            u1[1][ks][r0 + reg + l2b][i2] = (short)(ul >> 16);
        }
    }
    __syncthreads();
    // GEMM2: pre2 = u1 @ wn2[l]  (K=256)
    f32x4 acc2[4];
#pragma unroll
    for (int nti = 0; nti < 4; ++nti) acc2[nti] = (f32x4){0.f, 0.f, 0.f, 0.f};
#pragma unroll
    for (int ks = 0; ks < 8; ++ks) {
        bf16x8 ah = *(const bf16x8*)&u1[0][ks][lane][0];
        bf16x8 al = *(const bf16x8*)&u1[1][ks][lane][0];
#pragma unroll
        for (int nti = 0; nti < 4; ++nti) {
            int nt = w * 4 + nti;
            bf16x8 bh = ((const bf16x8*)hwn2)[(nt * 8 + ks) * 64 + lane];
            bf16x8 bl = ((const bf16x8*)lwn2)[(nt * 8 + ks) * 64 + lane];
            acc2[nti] = __builtin_amdgcn_mfma_f32_16x16x32_bf16(ah, bh, acc2[nti], 0, 0, 0);
            acc2[nti] = __builtin_amdgcn_mfma_f32_16x16x32_bf16(al, bh, acc2[nti], 0, 0, 0);
            acc2[nti] = __builtin_amdgcn_mfma_f32_16x16x32_bf16(ah, bl, acc2[nti], 0, 0, 0);
        }
    }
    // epilogue2: xnew = pre2 + bn2 + x_old (reconstructed hi+lo from cat)
#pragma unroll
    for (int nti = 0; nti < 4; ++nti) {
        int col = w * 64 + nti * 16 + (lane & 15);
        float bias = bn2[col];
        int ks = col >> 5, l2b = 16 * ((col & 31) >> 3), i2 = col & 7;
#pragma unroll
        for (int reg = 0; reg < 4; ++reg) {
            int lane2 = r0 + reg + l2b;
            float xold = bfraw2f((unsigned short)cat[0][ks][lane2][i2])
                       + bfraw2f((unsigned short)cat[1][ks][lane2][i2]);
            float xv = acc2[nti][reg] + bias + xold;
            unsigned uh, ul;
            split_tr(xv, uh, ul);
            xn[0][ks][lane2][i2] = (short)(uh >> 16);
            xn[1][ks][lane2][i2] = (short)(ul >> 16);
        }
    }
    __syncthreads();
    if (!last) {
        // dump xn -> xs
#pragma unroll
        for (int rep = 0; rep < 4; ++rep) {
            int s = rep * 256 + t;
            int plane = s >> 9, ks = (s >> 6) & 7, ln = s & 63;
            bf16x8 v = *(const bf16x8*)&xn[plane][ks][ln][0];
            bf16x8* dstp = (bf16x8*)(plane ? xs_lo : xs_hi);
            dstp[(size_t)(mt * 8 + ks) * 64 + ln] = v;
        }
        // GEMM3: [A|B] = xnew @ we1[l+1]
        f32x4 acc3[4];
#pragma unroll
        for (int nti = 0; nti < 4; ++nti) acc3[nti] = (f32x4){0.f, 0.f, 0.f, 0.f};
#pragma unroll
        for (int ks = 0; ks < 8; ++ks) {
            bf16x8 ah = *(const bf16x8*)&xn[0][ks][lane][0];
            bf16x8 al = *(const bf16x8*)&xn[1][ks][lane][0];
#pragma unroll
            for (int nti = 0; nti < 4; ++nti) {
                int nt = w * 4 + nti;
                bf16x8 bh = ((const bf16x8*)hwe1)[(nt * 8 + ks) * 64 + lane];
                bf16x8 bl = ((const bf16x8*)lwe1)[(nt * 8 + ks) * 64 + lane];
                acc3[nti] = __builtin_amdgcn_mfma_f32_16x16x32_bf16(ah, bh, acc3[nti], 0, 0, 0);
                acc3[nti] = __builtin_amdgcn_mfma_f32_16x16x32_bf16(al, bh, acc3[nti], 0, 0, 0);
                acc3[nti] = __builtin_amdgcn_mfma_f32_16x16x32_bf16(ah, bl, acc3[nti], 0, 0, 0);
            }
        }
#pragma unroll
        for (int nti = 0; nti < 4; ++nti) {
            int j = w * 64 + nti * 16 + (lane & 15);
            float bias = (j < 128) ? be1[j] : 0.0f;
            float* dstp = (j < 128) ? A : Bb;
            int jj = j & 127;
#pragma unroll
            for (int reg = 0; reg < 4; ++reg) {
                int node = n0 + r0 + reg;
                dstp[(size_t)node * 128 + jj] = acc3[nti][reg] + bias;
            }
        }
    } else {
        // GEMM_out: out = xnew @ w_out + b_out  (N=64: wave w -> nt=w)
        f32x4 acco = {0.f, 0.f, 0.f, 0.f};
#pragma unroll
        for (int ks = 0; ks < 8; ++ks) {
            bf16x8 ah = *(const bf16x8*)&xn[0][ks][lane][0];
            bf16x8 al = *(const bf16x8*)&xn[1][ks][lane][0];
            bf16x8 bh = ((const bf16x8*)hwout)[(w * 8 + ks) * 64 + lane];
            bf16x8 bl = ((const bf16x8*)lwout)[(w * 8 + ks) * 64 + lane];
            acco = __builtin_amdgcn_mfma_f32_16x16x32_bf16(ah, bh, acco, 0, 0, 0);
            acco = __builtin_amdgcn_mfma_f32_16x16x32_bf16(al, bh, acco, 0, 0, 0);
            acco = __builtin_amdgcn_mfma_f32_16x16x32_bf16(ah, bl, acco, 0, 0, 0);
        }
        int col = w * 16 + (lane & 15);
        float bias = b_out[col];
#pragma unroll
        for (int reg = 0; reg < 4; ++reg) {
            outp[(size_t)(n0 + r0 + reg) * ONF + col] = acco[reg] + bias;
        }
    }
}

extern "C" void kernel_launch(void* const* d_in, const int* in_sizes, int n_in,
                              void* d_out, int out_size, void* d_ws, size_t ws_size,
                              hipStream_t stream) {
    const float* h     = (const float*)d_in[0];
    const float* w_in  = (const float*)d_in[3];
    const float* b_in  = (const float*)d_in[4];
    const float* w_out = (const float*)d_in[5];
    const float* b_out = (const float*)d_in[6];
    const float* we1   = (const float*)d_in[7];
    const float* be1   = (const float*)d_in[8];
    const float* we2   = (const float*)d_in[9];
    const float* be2   = (const float*)d_in[10];
    const float* wn1   = (const float*)d_in[11];
    const float* bn1   = (const float*)d_in[12];
    const float* wn2   = (const float*)d_in[13];
    const float* bn2   = (const float*)d_in[14];

    float* A    = (float*)d_ws;              // 2048*128
    float* Bb   = A + 262144;                // 2048*128
    float* agg  = Bb + 262144;               // 2048*128
    short* xs_hi = (short*)(agg + 262144);   // 2048*256
    short* xs_lo = xs_hi + 524288;
    short* hwin  = xs_lo + 524288;           // 2048*8
    short* lwin  = hwin + 16384;
    short* hwe1  = lwin + 16384;             // 4*8192*8
    short* lwe1  = hwe1 + 262144;
    short* hwn1  = lwe1 + 262144;            // 4*12288*8
    short* lwn1  = hwn1 + 393216;
    short* hwn2  = lwn1 + 393216;            // 4*8192*8
    short* lwn2  = hwn2 + 262144;
    short* hwout = lwn2 + 262144;            // 2048*8
    short* lwout = hwout + 16384;
    short* hwe2  = lwout + 16384;            // 4*2048*8
    short* lwe2  = hwe2 + 65536;
    float* outp  = (float*)d_out;

    k_prep<<<496, 256, 0, stream>>>(w_in, we1, wn1, wn2, w_out, we2,
        hwin, lwin, hwe1, lwe1, hwn1, lwn1, hwn2, lwn2, hwout, lwout, hwe2, lwe2);
    k_embed_ab<<<128, 256, 0, stream>>>(h, b_in, be1, hwin, lwin, hwe1, lwe1,
        xs_hi, xs_lo, A, Bb);
    for (int l = 0; l < NL; ++l) {
        const int last = (l == NL - 1);
        const int lp = last ? 0 : (l + 1);
        k_edge_mfma<<<NTOT, 256, 0, stream>>>(A, Bb,
            hwe2 + (size_t)l * 2048 * 8, lwe2 + (size_t)l * 2048 * 8,
            be2 + l * EHD, agg);
        k_node_ab<<<128, 256, 0, stream>>>(agg,
            bn1 + l * HD, bn2 + l * HD, be1 + lp * EHD, b_out,
            hwn1 + (size_t)l * 12288 * 8, lwn1 + (size_t)l * 12288 * 8,
            hwn2 + (size_t)l * 8192 * 8, lwn2 + (size_t)l * 8192 * 8,
            hwe1 + (size_t)lp * 8192 * 8, lwe1 + (size_t)lp * 8192 * 8,
            hwout, lwout, xs_hi, xs_lo, A, Bb, outp, last);
    }
}